// Round 1
// baseline (8173.800 us; speedup 1.0000x reference)
//
#include <hip/hip_runtime.h>
#include <stdint.h>

typedef _Float16 f16x8 __attribute__((ext_vector_type(8)));
typedef _Float16 f16x4 __attribute__((ext_vector_type(4)));
typedef float    f32x4 __attribute__((ext_vector_type(4)));

// Problem constants
#define T_LEN 512
#define BATCH 128
#define DH    512
#define NC    1024          // combined gate columns (z: 0..511, n: 512..1023)
#define IZ_BLK 131072       // NC*BATCH f16 elements per t-block of izin (= 256KB)

// ---------------------------------------------------------------------------
// async global->LDS helper (16B per lane; LDS dest = wave-uniform base + lane*16)
// ---------------------------------------------------------------------------
__device__ __forceinline__ void gload_lds16(const void* gsrc, void* ldsdst) {
    auto g = (const __attribute__((address_space(1))) void*)(reinterpret_cast<uintptr_t>(gsrc));
    auto s = (__attribute__((address_space(3))) void*)(reinterpret_cast<uintptr_t>(ldsdst));
    __builtin_amdgcn_global_load_lds(g, s, 16, 0, 0);
}

// ---------------------------------------------------------------------------
// prep: build f16 weights (Wci = [W_iz;W_in], Whc = [W_hz;W_hn]), combined
// biases bc = b_i + b_h, zero hbuf[0], zero flags.  Runs every launch
// (flags/hbuf MUST be reset per call for graph replays).
// ---------------------------------------------------------------------------
__global__ __launch_bounds__(256) void prep_misc(
    const float* __restrict__ W_iz, const float* __restrict__ W_in,
    const float* __restrict__ W_hz, const float* __restrict__ W_hn,
    const float* __restrict__ b_iz, const float* __restrict__ b_in,
    const float* __restrict__ b_hz, const float* __restrict__ b_hn,
    _Float16* __restrict__ Wci, _Float16* __restrict__ Whc,
    float* __restrict__ bc, _Float16* __restrict__ hbuf, int* __restrict__ flags)
{
    const int tid = blockIdx.x * 256 + threadIdx.x;
    if (tid < 131072) {                      // 2 * 1024*512/8 weight vector units
        const bool is_h = tid >= 65536;
        const int u = tid & 65535;
        const int e = u * 8;
        const int row = e >> 9;              // j2 in [0,1024)
        const int k = e & 511;
        const float* s;
        if (!is_h) s = (row < 512) ? (W_iz + (size_t)row * 512 + k)
                                   : (W_in + (size_t)(row - 512) * 512 + k);
        else       s = (row < 512) ? (W_hz + (size_t)row * 512 + k)
                                   : (W_hn + (size_t)(row - 512) * 512 + k);
        f32x4 a = *(const f32x4*)s;
        f32x4 b = *(const f32x4*)(s + 4);
        f16x8 o;
        o[0] = (_Float16)a[0]; o[1] = (_Float16)a[1];
        o[2] = (_Float16)a[2]; o[3] = (_Float16)a[3];
        o[4] = (_Float16)b[0]; o[5] = (_Float16)b[1];
        o[6] = (_Float16)b[2]; o[7] = (_Float16)b[3];
        _Float16* d = is_h ? Whc : Wci;
        *(f16x8*)(d + e) = o;
    } else if (tid < 132096) {               // 1024 combined biases
        const int j2 = tid - 131072;
        bc[j2] = (j2 < 512) ? (b_iz[j2] + b_hz[j2]) : (b_in[j2 - 512] + b_hn[j2 - 512]);
    } else if (tid < 140288) {               // zero hbuf[0] : 65536 f16 / 8
        const int u = tid - 132096;
        f16x8 z = { (_Float16)0, (_Float16)0, (_Float16)0, (_Float16)0,
                    (_Float16)0, (_Float16)0, (_Float16)0, (_Float16)0 };
        *(f16x8*)(hbuf + (size_t)u * 8) = z;
    } else if (tid < 140544) {               // 256 flags
        flags[tid - 140288] = 0;
    }
}

// ---------------------------------------------------------------------------
// Phase 1: izin_w[t][j2][b] (f16, into d_out) = seq[t,b,:] . Wci[j2,:] + bc[j2]
// 128x128 tile, BK=32, 4 waves (2x2 of 64x64), f16 MFMA 16x16x32.
// A (seq f32) reg-staged + converted, padded LDS stride 40 f16 (conflict-free-ish).
// B (Wci f16) via global_load_lds, linear LDS.
// ---------------------------------------------------------------------------
__global__ __launch_bounds__(256) void gemm_proj(
    const float* __restrict__ A,      // seq as [65536][512] f32 (row = t*128+b)
    const _Float16* __restrict__ Bw,  // Wci [1024][512] f16
    const float* __restrict__ bc,     // [1024] f32
    _Float16* Co)                     // izin_w (= d_out as f16)
{
    __shared__ _Float16 As[128 * 40];   // padded stride 40 f16 (80B)
    __shared__ _Float16 Bs[128 * 32];   // linear (global_load_lds target)

    const int mt = blockIdx.x;          // = t   (one 128-row tile == one timestep)
    const int nt = blockIdx.y;          // 0..7
    const int m0 = mt * 128, n0 = nt * 128;
    const int tid = threadIdx.x;
    const int w = tid >> 6, l = tid & 63;
    const int wr = w >> 1, wc = w & 1;
    const int lrow = l & 15, lk = l >> 4;

    f32x4 acc[4][4] = {};

    const int arow = tid >> 1;            // 0..127
    const int acol = (tid & 1) * 16;      // 0 or 16

    for (int kt = 0; kt < 16; ++kt) {
        const int k0 = kt * 32;
        if (kt) __syncthreads();
        // --- stage A: f32 -> f16 into padded LDS
        const float* as = A + (size_t)(m0 + arow) * 512 + k0 + acol;
        f32x4 a0 = *(const f32x4*)as;
        f32x4 a1 = *(const f32x4*)(as + 4);
        f32x4 a2 = *(const f32x4*)(as + 8);
        f32x4 a3 = *(const f32x4*)(as + 12);
        f16x8 h0, h1;
#pragma unroll
        for (int e = 0; e < 4; ++e) {
            h0[e] = (_Float16)a0[e]; h0[4 + e] = (_Float16)a1[e];
            h1[e] = (_Float16)a2[e]; h1[4 + e] = (_Float16)a3[e];
        }
        *(f16x8*)&As[arow * 40 + acol] = h0;
        *(f16x8*)&As[arow * 40 + acol + 8] = h1;
        // --- stage B via async direct-to-LDS (wave w covers 1KB chunks 2w, 2w+1)
#pragma unroll
        for (int i = 0; i < 2; ++i) {
            const int chunk = w * 2 + i;
            const _Float16* gsrc =
                Bw + (size_t)(n0 + chunk * 16 + (l >> 2)) * 512 + k0 + (l & 3) * 8;
            gload_lds16(gsrc, &Bs[chunk * 512]);
        }
        __syncthreads();
        // --- fragments + MFMA
        f16x8 af[4], bf[4];
#pragma unroll
        for (int i = 0; i < 4; ++i) {
            af[i] = *(const f16x8*)&As[(wr * 64 + i * 16 + lrow) * 40 + lk * 8];
            bf[i] = *(const f16x8*)&Bs[(wc * 64 + i * 16 + lrow) * 32 + lk * 8];
        }
#pragma unroll
        for (int mi = 0; mi < 4; ++mi)
#pragma unroll
            for (int ni = 0; ni < 4; ++ni)
                acc[mi][ni] = __builtin_amdgcn_mfma_f32_16x16x32_f16(
                    af[mi], bf[ni], acc[mi][ni], 0, 0, 0);
    }
    // --- epilogue: add bias, cvt f16, store TRANSPOSED: izin_w[t][j2][b]
#pragma unroll
    for (int ni = 0; ni < 4; ++ni) {
        const int j2 = n0 + wc * 64 + ni * 16 + lrow;
        const float bias = bc[j2];
#pragma unroll
        for (int mi = 0; mi < 4; ++mi) {
            const int brow = wr * 64 + mi * 16 + lk * 4;   // batch row base (mult of 4)
            f16x4 o;
#pragma unroll
            for (int r = 0; r < 4; ++r) o[r] = (_Float16)(acc[mi][ni][r] + bias);
            *(f16x4*)&Co[(size_t)mt * IZ_BLK + (size_t)j2 * 128 + brow] = o;
        }
    }
}

// ---------------------------------------------------------------------------
// Phase 2: persistent recurrent scan.
// 256 WGs x 64 threads (1 wave). group g = blk>>5 owns batch rows [16g,16g+16).
// WG slot w = blk&31 owns hidden cols [16w,16w+16), BOTH gates.
// Weights live in registers (32 x f16x8 = 128 VGPRs); h master (f32) in regs.
// Per-step sync: per-WG monotonic flag; 32 lanes poll the group's 32 flags.
// izin is read one step AHEAD of the H (f32) overwrite of the same d_out block;
// the flag barrier orders prefetch-completion before any H[t] write.
// ---------------------------------------------------------------------------
__global__ __launch_bounds__(64, 1) void gru_scan(
    const _Float16* __restrict__ Whc,   // [1024][512] f16 (rows 0-511 = W_hz)
    const _Float16* izin,               // d_out viewed as f16  [t][j2][b]
    float* Hout,                        // d_out viewed as f32  [t][b][j]
    _Float16* __restrict__ hbuf,        // [2][128][512] f16
    int* flags)                         // [8][32]
{
    const int blk = blockIdx.x;
    const int g = blk >> 5;
    const int wslot = blk & 31;
    const int l = threadIdx.x;
    const int j0 = wslot * 16;
    const int lrow = l & 15;    // A-row (batch) / B-row (col j) lane index
    const int lk = l >> 4;      // k-chunk; also C-row quad base
    const int fi = g * 32 + (l & 31);
    const int myflag = g * 32 + wslot;

    // persistent register-resident weights
    f16x8 wz[16], wn[16];
#pragma unroll
    for (int s = 0; s < 16; ++s) {
        wz[s] = *(const f16x8*)&Whc[(size_t)(j0 + lrow) * 512 + s * 32 + lk * 8];
        wn[s] = *(const f16x8*)&Whc[(size_t)(512 + j0 + lrow) * 512 + s * 32 + lk * 8];
    }
    float hm[4] = {0.f, 0.f, 0.f, 0.f};   // f32 master h for (b = 16g+4*lk+r, j = j0+lrow)

    // prefetch izin[0]
    f16x4 pz = *(const f16x4*)&izin[(size_t)(j0 + lrow) * 128 + g * 16 + lk * 4];
    f16x4 pn = *(const f16x4*)&izin[(size_t)(512 + j0 + lrow) * 128 + g * 16 + lk * 4];

    __threadfence();   // completes prefetch loads + publishes nothing yet (vmcnt drain)
    if (l == 0)
        __hip_atomic_store(&flags[myflag], 1, __ATOMIC_RELAXED, __HIP_MEMORY_SCOPE_AGENT);

    for (int t = 0; t < T_LEN; ++t) {
        // ---- group barrier: wait until all 32 WGs reached phase t+1
        const int target = t + 1;
        while (true) {
            int v = __hip_atomic_load(&flags[fi], __ATOMIC_RELAXED, __HIP_MEMORY_SCOPE_AGENT);
            if (__all(v >= target)) break;
            __builtin_amdgcn_s_sleep(1);
        }
        __threadfence();   // acquire: invalidate stale cache lines before h reads

        // ---- load h_t fragments (group's 16 rows, all 512 k) and run MFMAs
        const _Float16* hb = hbuf + (size_t)(t & 1) * 65536 + (size_t)(g * 16) * 512;
        f32x4 az = {0.f, 0.f, 0.f, 0.f}, an = {0.f, 0.f, 0.f, 0.f};
#pragma unroll
        for (int s = 0; s < 16; ++s) {
            f16x8 hf = *(const f16x8*)&hb[(size_t)lrow * 512 + s * 32 + lk * 8];
            az = __builtin_amdgcn_mfma_f32_16x16x32_f16(hf, wz[s], az, 0, 0, 0);
            an = __builtin_amdgcn_mfma_f32_16x16x32_f16(hf, wn[s], an, 0, 0, 0);
        }

        // ---- prefetch izin[t+1] (block t+1 of d_out is still pristine f16)
        f16x4 npz = {(_Float16)0, (_Float16)0, (_Float16)0, (_Float16)0};
        f16x4 npn = npz;
        if (t < T_LEN - 1) {
            const size_t nb = (size_t)(t + 1) * IZ_BLK;
            npz = *(const f16x4*)&izin[nb + (size_t)(j0 + lrow) * 128 + g * 16 + lk * 4];
            npn = *(const f16x4*)&izin[nb + (size_t)(512 + j0 + lrow) * 128 + g * 16 + lk * 4];
        }

        // ---- gates + state update (f32), write H[t] (f32) and h broadcast (f16)
        float* Hrow = Hout + (size_t)t * 65536;
        _Float16* hw = hbuf + (size_t)((t + 1) & 1) * 65536;
#pragma unroll
        for (int r = 0; r < 4; ++r) {
            float zpre = az[r] + (float)pz[r];
            float npre = an[r] + (float)pn[r];
            zpre = fminf(fmaxf(zpre, -30.f), 30.f);
            const float z = 1.f / (1.f + __expf(-zpre));
            npre = fminf(fmaxf(npre, -15.f), 15.f);
            const float e2 = __expf(2.f * npre);
            const float n = (e2 - 1.f) / (e2 + 1.f);
            hm[r] = (1.f - z) * n + z * hm[r];
            const size_t bi = (size_t)(g * 16 + lk * 4 + r);
            Hrow[bi * 512 + j0 + lrow] = hm[r];
            hw[bi * 512 + j0 + lrow] = (_Float16)hm[r];
        }
        pz = npz; pn = npn;

        __threadfence();   // release: drain loads+stores, write back L2
        if (l == 0)
            __hip_atomic_store(&flags[myflag], t + 2, __ATOMIC_RELAXED, __HIP_MEMORY_SCOPE_AGENT);
    }
}

// ---------------------------------------------------------------------------
extern "C" void kernel_launch(void* const* d_in, const int* in_sizes, int n_in,
                              void* d_out, int out_size, void* d_ws, size_t ws_size,
                              hipStream_t stream) {
    (void)in_sizes; (void)n_in; (void)out_size; (void)ws_size;
    const float* seq  = (const float*)d_in[0];
    const float* W_iz = (const float*)d_in[1];
    const float* b_iz = (const float*)d_in[2];
    const float* W_in = (const float*)d_in[3];
    const float* b_in = (const float*)d_in[4];
    const float* W_hz = (const float*)d_in[5];
    const float* b_hz = (const float*)d_in[6];
    const float* W_hn = (const float*)d_in[7];
    const float* b_hn = (const float*)d_in[8];

    char* ws = (char*)d_ws;                       // total use: ~2.3 MB
    _Float16* Wci  = (_Float16*)(ws);             // 1,048,576 B
    _Float16* Whc  = (_Float16*)(ws + 1048576);   // 1,048,576 B
    float*    bc   = (float*)   (ws + 2097152);   //     4,096 B
    _Float16* hbuf = (_Float16*)(ws + 2101248);   //   262,144 B
    int*      flags= (int*)     (ws + 2363392);   //     1,024 B

    prep_misc<<<549, 256, 0, stream>>>(W_iz, W_in, W_hz, W_hn,
                                       b_iz, b_in, b_hz, b_hn,
                                       Wci, Whc, bc, hbuf, flags);
    gemm_proj<<<dim3(512, 8), 256, 0, stream>>>(seq, Wci, bc, (_Float16*)d_out);
    gru_scan<<<256, 64, 0, stream>>>(Whc, (const _Float16*)d_out, (float*)d_out,
                                     hbuf, flags);
}

// Round 2
// 2566.253 us; speedup vs baseline: 3.1851x; 3.1851x over previous
//
#include <hip/hip_runtime.h>
#include <stdint.h>

typedef _Float16 f16x8 __attribute__((ext_vector_type(8)));
typedef _Float16 f16x4 __attribute__((ext_vector_type(4)));
typedef float    f32x4 __attribute__((ext_vector_type(4)));

// Problem constants
#define T_LEN 512
#define BATCH 128
#define DH    512
#define NC    1024          // combined gate columns (z: 0..511, n: 512..1023)
#define IZ_BLK 131072       // NC*BATCH f16 elements per t-block of izin (= 256KB)

union U64x1 { unsigned long long u; f16x4 v; };
union U64x2 { unsigned long long u[2]; f16x8 v; };

// ---------------------------------------------------------------------------
// async global->LDS helper (16B per lane; LDS dest = wave-uniform base + lane*16)
// ---------------------------------------------------------------------------
__device__ __forceinline__ void gload_lds16(const void* gsrc, void* ldsdst) {
    auto g = (const __attribute__((address_space(1))) void*)(reinterpret_cast<uintptr_t>(gsrc));
    auto s = (__attribute__((address_space(3))) void*)(reinterpret_cast<uintptr_t>(ldsdst));
    __builtin_amdgcn_global_load_lds(g, s, 16, 0, 0);
}

// ---------------------------------------------------------------------------
// prep: f16 weights (Wci=[W_iz;W_in], Whc=[W_hz;W_hn]), bc = b_i+b_h,
// zero hbuf[0], zero flags.  Must run every launch (graph replays).
// ---------------------------------------------------------------------------
__global__ __launch_bounds__(256) void prep_misc(
    const float* __restrict__ W_iz, const float* __restrict__ W_in,
    const float* __restrict__ W_hz, const float* __restrict__ W_hn,
    const float* __restrict__ b_iz, const float* __restrict__ b_in,
    const float* __restrict__ b_hz, const float* __restrict__ b_hn,
    _Float16* __restrict__ Wci, _Float16* __restrict__ Whc,
    float* __restrict__ bc, _Float16* __restrict__ hbuf, int* __restrict__ flags)
{
    const int tid = blockIdx.x * 256 + threadIdx.x;
    if (tid < 131072) {                      // 2 * 1024*512/8 weight vector units
        const bool is_h = tid >= 65536;
        const int u = tid & 65535;
        const int e = u * 8;
        const int row = e >> 9;              // j2 in [0,1024)
        const int k = e & 511;
        const float* s;
        if (!is_h) s = (row < 512) ? (W_iz + (size_t)row * 512 + k)
                                   : (W_in + (size_t)(row - 512) * 512 + k);
        else       s = (row < 512) ? (W_hz + (size_t)row * 512 + k)
                                   : (W_hn + (size_t)(row - 512) * 512 + k);
        f32x4 a = *(const f32x4*)s;
        f32x4 b = *(const f32x4*)(s + 4);
        f16x8 o;
        o[0] = (_Float16)a[0]; o[1] = (_Float16)a[1];
        o[2] = (_Float16)a[2]; o[3] = (_Float16)a[3];
        o[4] = (_Float16)b[0]; o[5] = (_Float16)b[1];
        o[6] = (_Float16)b[2]; o[7] = (_Float16)b[3];
        _Float16* d = is_h ? Whc : Wci;
        *(f16x8*)(d + e) = o;
    } else if (tid < 132096) {               // 1024 combined biases
        const int j2 = tid - 131072;
        bc[j2] = (j2 < 512) ? (b_iz[j2] + b_hz[j2]) : (b_in[j2 - 512] + b_hn[j2 - 512]);
    } else if (tid < 140288) {               // zero hbuf[0] : 65536 f16 / 8
        const int u = tid - 132096;
        f16x8 z = { (_Float16)0, (_Float16)0, (_Float16)0, (_Float16)0,
                    (_Float16)0, (_Float16)0, (_Float16)0, (_Float16)0 };
        *(f16x8*)(hbuf + (size_t)u * 8) = z;
    } else if (tid < 140544) {               // 256 flags
        flags[tid - 140288] = 0;
    }
}

// ---------------------------------------------------------------------------
// Phase 1: izin[t][b][j2] (f16, into d_out) = seq[t,b,:] . Wci[j2,:] + bc[j2]
// 128x128 tile, BK=32, 4 waves (2x2 of 64x64), f16 MFMA 16x16x32.
// Operand order mfma(B,A): D rows = j2 quads, D cols = b  -> row-major C store.
// ---------------------------------------------------------------------------
__global__ __launch_bounds__(256) void gemm_proj(
    const float* __restrict__ A,      // seq as [65536][512] f32 (row = t*128+b)
    const _Float16* __restrict__ Bw,  // Wci [1024][512] f16
    const float* __restrict__ bc,     // [1024] f32
    _Float16* Co)                     // izin (= d_out as f16), [t*128+b][1024]
{
    __shared__ _Float16 As[128 * 40];   // padded stride 40 f16
    __shared__ _Float16 Bs[128 * 32];   // linear (global_load_lds target)

    const int mt = blockIdx.x;          // = t
    const int nt = blockIdx.y;          // 0..7
    const int m0 = mt * 128, n0 = nt * 128;
    const int tid = threadIdx.x;
    const int w = tid >> 6, l = tid & 63;
    const int wr = w >> 1, wc = w & 1;
    const int lrow = l & 15, lk = l >> 4;

    f32x4 acc[4][4] = {};

    const int arow = tid >> 1;            // 0..127
    const int acol = (tid & 1) * 16;      // 0 or 16

    for (int kt = 0; kt < 16; ++kt) {
        const int k0 = kt * 32;
        if (kt) __syncthreads();
        // --- stage A: f32 -> f16 into padded LDS
        const float* as = A + (size_t)(m0 + arow) * 512 + k0 + acol;
        f32x4 a0 = *(const f32x4*)as;
        f32x4 a1 = *(const f32x4*)(as + 4);
        f32x4 a2 = *(const f32x4*)(as + 8);
        f32x4 a3 = *(const f32x4*)(as + 12);
        f16x8 h0, h1;
#pragma unroll
        for (int e = 0; e < 4; ++e) {
            h0[e] = (_Float16)a0[e]; h0[4 + e] = (_Float16)a1[e];
            h1[e] = (_Float16)a2[e]; h1[4 + e] = (_Float16)a3[e];
        }
        *(f16x8*)&As[arow * 40 + acol] = h0;
        *(f16x8*)&As[arow * 40 + acol + 8] = h1;
        // --- stage B via async direct-to-LDS
#pragma unroll
        for (int i = 0; i < 2; ++i) {
            const int chunk = w * 2 + i;
            const _Float16* gsrc =
                Bw + (size_t)(n0 + chunk * 16 + (l >> 2)) * 512 + k0 + (l & 3) * 8;
            gload_lds16(gsrc, &Bs[chunk * 512]);
        }
        __syncthreads();
        // --- fragments + MFMA (swapped operands: rows=j2, cols=b)
        f16x8 af[4], bf[4];
#pragma unroll
        for (int i = 0; i < 4; ++i) {
            af[i] = *(const f16x8*)&As[(wr * 64 + i * 16 + lrow) * 40 + lk * 8];
            bf[i] = *(const f16x8*)&Bs[(wc * 64 + i * 16 + lrow) * 32 + lk * 8];
        }
#pragma unroll
        for (int mi = 0; mi < 4; ++mi)
#pragma unroll
            for (int ni = 0; ni < 4; ++ni)
                acc[mi][ni] = __builtin_amdgcn_mfma_f32_16x16x32_f16(
                    bf[ni], af[mi], acc[mi][ni], 0, 0, 0);
    }
    // --- epilogue: bias, cvt f16, row-major store Co[t*128+b][j2]
#pragma unroll
    for (int ni = 0; ni < 4; ++ni) {
        const int j2q = n0 + wc * 64 + ni * 16 + 4 * lk;   // j2 quad base
        const f32x4 bb = *(const f32x4*)&bc[j2q];
#pragma unroll
        for (int mi = 0; mi < 4; ++mi) {
            const int brow = wr * 64 + mi * 16 + lrow;     // b within 128
            f16x4 o;
#pragma unroll
            for (int r = 0; r < 4; ++r) o[r] = (_Float16)(acc[mi][ni][r] + bb[r]);
            *(f16x4*)&Co[((size_t)mt * 128 + brow) * 1024 + j2q] = o;
        }
    }
}

// ---------------------------------------------------------------------------
// Phase 2: persistent recurrent scan — NO cache-flush fences.
// 256 WGs x 1 wave. group g = blk>>5 owns batch rows [16g,16g+16);
// slot w = blk&31 owns hidden cols [16w,16w+16), both gates.
// All cross-WG traffic via relaxed agent-scope atomics (write-through LLC):
//   h exchange: u64 granules in hbuf [2][128][512] f16 (row-major [b][j]).
// Ordering: data atomics -> s_waitcnt vmcnt(0) -> relaxed flag store.
// Lane l: b = 16g + (l&15), j quad = 16w + 4*(l>>4).
// mfma(W, h): D rows = j (quad per lane), D cols = b.
// ---------------------------------------------------------------------------
__global__ __launch_bounds__(64, 1) void gru_scan(
    const _Float16* __restrict__ Whc,   // [1024][512] f16 (rows 0-511 = W_hz)
    const _Float16* izin,               // d_out viewed as f16  [t][b][j2]
    float* Hout,                        // d_out viewed as f32  [t][b][j]
    _Float16* hbuf,                     // [2][128][512] f16
    int* flags)                         // [8][32]
{
    const int blk = blockIdx.x;
    const int g = blk >> 5;
    const int wslot = blk & 31;
    const int l = threadIdx.x;
    const int j0 = wslot * 16;
    const int lrow = l & 15;
    const int lk = l >> 4;
    const int b = g * 16 + lrow;        // this lane's batch row
    const int jq = j0 + 4 * lk;         // this lane's j quad base
    const int fi = g * 32 + (l & 31);
    const int myflag = g * 32 + wslot;

    // persistent register-resident weights: W rows j0+lrow (z) / 512+j0+lrow (n)
    f16x8 wz[16], wn[16];
#pragma unroll
    for (int s = 0; s < 16; ++s) {
        wz[s] = *(const f16x8*)&Whc[(size_t)(j0 + lrow) * 512 + s * 32 + lk * 8];
        wn[s] = *(const f16x8*)&Whc[(size_t)(512 + j0 + lrow) * 512 + s * 32 + lk * 8];
    }
    float hm[4] = {0.f, 0.f, 0.f, 0.f};   // h[b][jq + r]

    // prefetch izin[0] (plain loads; written by gemm_proj, kernel-order visible)
    f16x4 pz = *(const f16x4*)&izin[(size_t)b * 1024 + jq];
    f16x4 pn = *(const f16x4*)&izin[(size_t)b * 1024 + 512 + jq];

    asm volatile("s_waitcnt vmcnt(0)" ::: "memory");
    if (l == 0)
        __hip_atomic_store(&flags[myflag], 1, __ATOMIC_RELAXED, __HIP_MEMORY_SCOPE_AGENT);

    for (int t = 0; t < T_LEN; ++t) {
        // ---- group barrier: all 32 WGs of group g at phase >= t+1
        const int target = t + 1;
        while (true) {
            int v = __hip_atomic_load(&flags[fi], __ATOMIC_RELAXED, __HIP_MEMORY_SCOPE_AGENT);
            if (__all(v >= target)) break;
            __builtin_amdgcn_s_sleep(1);
        }
        asm volatile("" ::: "memory");   // compiler fence only (HW order via data dep)

        // ---- issue izin[t+1] prefetch early (overlaps h-load LLC round trip).
        //      Safe: H[t+1] writers need ALL flags >= t+2; ours comes after vmcnt(0).
        f16x4 npz = {(_Float16)0, (_Float16)0, (_Float16)0, (_Float16)0};
        f16x4 npn = npz;
        if (t < T_LEN - 1) {
            const size_t nb = (size_t)(t + 1) * IZ_BLK + (size_t)b * 1024;
            npz = *(const f16x4*)&izin[nb + jq];
            npn = *(const f16x4*)&izin[nb + 512 + jq];
        }

        // ---- load h_t fragments (coherent u64 atomics) + MFMA
        const unsigned long long* hr = (const unsigned long long*)
            (hbuf + (size_t)(t & 1) * 65536 + (size_t)b * 512 + lk * 8);
        f32x4 az = {0.f, 0.f, 0.f, 0.f}, an = {0.f, 0.f, 0.f, 0.f};
#pragma unroll
        for (int s = 0; s < 16; ++s) {
            U64x2 hu;
            hu.u[0] = __hip_atomic_load(hr + s * 8,     __ATOMIC_RELAXED, __HIP_MEMORY_SCOPE_AGENT);
            hu.u[1] = __hip_atomic_load(hr + s * 8 + 1, __ATOMIC_RELAXED, __HIP_MEMORY_SCOPE_AGENT);
            az = __builtin_amdgcn_mfma_f32_16x16x32_f16(wz[s], hu.v, az, 0, 0, 0);
            an = __builtin_amdgcn_mfma_f32_16x16x32_f16(wn[s], hu.v, an, 0, 0, 0);
        }

        // ---- gates + state update (f32)
        f32x4 Hv;
        f16x4 hv;
#pragma unroll
        for (int r = 0; r < 4; ++r) {
            float zpre = az[r] + (float)pz[r];
            float npre = an[r] + (float)pn[r];
            zpre = fminf(fmaxf(zpre, -30.f), 30.f);
            const float z = 1.f / (1.f + __expf(-zpre));
            npre = fminf(fmaxf(npre, -15.f), 15.f);
            const float e2 = __expf(2.f * npre);
            const float n = (e2 - 1.f) / (e2 + 1.f);
            hm[r] = (1.f - z) * n + z * hm[r];
            Hv[r] = hm[r];
            hv[r] = (_Float16)hm[r];
        }

        // ---- publish h_{t+1} (one u64 write-through atomic per lane)
        U64x1 hc; hc.v = hv;
        __hip_atomic_store(
            (unsigned long long*)(hbuf + (size_t)((t + 1) & 1) * 65536 + (size_t)b * 512 + jq),
            hc.u, __ATOMIC_RELAXED, __HIP_MEMORY_SCOPE_AGENT);

        // drain h stores + izin prefetch, then signal
        asm volatile("s_waitcnt vmcnt(0)" ::: "memory");
        if (l == 0)
            __hip_atomic_store(&flags[myflag], t + 2, __ATOMIC_RELAXED, __HIP_MEMORY_SCOPE_AGENT);

        // ---- H[t] store (plain, off the critical path; ordering vs others'
        //      izin[t] prefetch was guaranteed by barrier t)
        *(f32x4*)&Hout[(size_t)t * 65536 + (size_t)b * 512 + jq] = Hv;

        pz = npz; pn = npn;
    }
}

// ---------------------------------------------------------------------------
extern "C" void kernel_launch(void* const* d_in, const int* in_sizes, int n_in,
                              void* d_out, int out_size, void* d_ws, size_t ws_size,
                              hipStream_t stream) {
    (void)in_sizes; (void)n_in; (void)out_size; (void)ws_size;
    const float* seq  = (const float*)d_in[0];
    const float* W_iz = (const float*)d_in[1];
    const float* b_iz = (const float*)d_in[2];
    const float* W_in = (const float*)d_in[3];
    const float* b_in = (const float*)d_in[4];
    const float* W_hz = (const float*)d_in[5];
    const float* b_hz = (const float*)d_in[6];
    const float* W_hn = (const float*)d_in[7];
    const float* b_hn = (const float*)d_in[8];

    char* ws = (char*)d_ws;                       // total use: ~2.3 MB
    _Float16* Wci  = (_Float16*)(ws);             // 1,048,576 B
    _Float16* Whc  = (_Float16*)(ws + 1048576);   // 1,048,576 B
    float*    bc   = (float*)   (ws + 2097152);   //     4,096 B
    _Float16* hbuf = (_Float16*)(ws + 2101248);   //   262,144 B
    int*      flags= (int*)     (ws + 2363392);   //     1,024 B

    prep_misc<<<549, 256, 0, stream>>>(W_iz, W_in, W_hz, W_hn,
                                       b_iz, b_in, b_hz, b_hn,
                                       Wci, Whc, bc, hbuf, flags);
    gemm_proj<<<dim3(512, 8), 256, 0, stream>>>(seq, Wci, bc, (_Float16*)d_out);
    gru_scan<<<256, 64, 0, stream>>>(Whc, (const _Float16*)d_out, (float*)d_out,
                                     hbuf, flags);
}